// Round 2
// baseline (121.189 us; speedup 1.0000x reference)
//
#include <hip/hip_runtime.h>
#include <hip/hip_cooperative_groups.h>
#include <math.h>

namespace cg = cooperative_groups;

// Problem constants (B=2, N_RES=512, N_ATOMS=4)
#define NPTS    2048                    // points per batch
#define BATCH   2
#define TOTAL_I (BATCH * NPTS)          // 4096
#define THREADS 256
#define IBLOCKS (TOTAL_I / THREADS)     // 16 i-groups
#define JCHUNKS 64
#define JLEN    (NPTS / JCHUNKS)        // 32 j-iterations per thread
#define NBLOCKS (IBLOCKS * JCHUNKS)     // 1024 blocks -> 4 per CU

__global__ __launch_bounds__(THREADS, 4) void fused_kernel(
    const float* __restrict__ pred, const float* __restrict__ nat,
    const int* __restrict__ mask, float* __restrict__ ws,
    float* __restrict__ out, float inv_d0)
{
    __shared__ float wsum[THREADS / 64];
    __shared__ float c0s[THREADS / 64], c1s[THREADS / 64];

    const int bid    = blockIdx.x;
    const int chunk  = bid / IBLOCKS;                 // 0..63, block-uniform
    const int igBase = (bid - chunk * IBLOCKS) * THREADS;
    const int b      = igBase / NPTS;                 // block-uniform batch
    const int i      = igBase - b * NPTS + threadIdx.x;
    const int lane   = threadIdx.x & 63;
    const int wid    = threadIdx.x >> 6;

    const float* __restrict__ pb = pred + (size_t)(b * NPTS * 3);
    const float* __restrict__ nb = nat  + (size_t)(b * NPTS * 3);
    const int*   __restrict__ mb = mask + b * NPTS;

    // per-lane i-point coords in registers
    const float pix = pb[i*3+0], piy = pb[i*3+1], piz = pb[i*3+2];
    const float nix = nb[i*3+0], niy = nb[i*3+1], niz = nb[i*3+2];
    const int   mi  = mb[i];

    float acc = 0.0f;
    const int j0 = chunk * JLEN;
    #pragma unroll 8
    for (int jj = 0; jj < JLEN; ++jj) {
        const int j = j0 + jj;                        // wave-uniform j stream
        const float dx = pix - pb[j*3+0];
        const float dy = piy - pb[j*3+1];
        const float dz = piz - pb[j*3+2];
        const float pd = __builtin_amdgcn_sqrtf(dx*dx + dy*dy + dz*dz);
        const float ex = nix - nb[j*3+0];
        const float ey = niy - nb[j*3+1];
        const float ez = niz - nb[j*3+2];
        const float nd = __builtin_amdgcn_sqrtf(ex*ex + ey*ey + ez*ez);
        const float t    = (pd - nd) * inv_d0;
        const float prox = __builtin_amdgcn_rcpf(1.0f + t*t);
        acc += (mb[j] != 0) ? prox : 0.0f;
    }
    if (mi == 0) acc = 0.0f;

    // wave reduce, then cross-wave via LDS; thread 0 writes block partial
    for (int off = 32; off > 0; off >>= 1)
        acc += __shfl_down(acc, off, 64);
    if (lane == 0) wsum[wid] = acc;
    __syncthreads();
    if (threadIdx.x == 0)
        ws[bid] = wsum[0] + wsum[1] + wsum[2] + wsum[3];

    // block 0 additionally computes the mask counts (cheap: 4096 ints)
    if (bid == 0) {
        int l0 = 0, l1 = 0;
        for (int k = threadIdx.x; k < NPTS; k += THREADS) {
            l0 += (mask[k] != 0);
            l1 += (mask[NPTS + k] != 0);
        }
        for (int off = 32; off > 0; off >>= 1) {
            l0 += __shfl_down(l0, off, 64);
            l1 += __shfl_down(l1, off, 64);
        }
        if (lane == 0) { c0s[wid] = (float)l0; c1s[wid] = (float)l1; }
        __syncthreads();
        if (threadIdx.x == 0) {
            ws[NBLOCKS]     = c0s[0] + c0s[1] + c0s[2] + c0s[3];
            ws[NBLOCKS + 1] = c1s[0] + c1s[1] + c1s[2] + c1s[3];
        }
    }

    cg::this_grid().sync();

    // block 0 reduces the 1024 partials and writes the scalar output
    if (bid == 0) {
        float s = ws[threadIdx.x] + ws[threadIdx.x + 256]
                + ws[threadIdx.x + 512] + ws[threadIdx.x + 768];
        for (int off = 32; off > 0; off >>= 1)
            s += __shfl_down(s, off, 64);
        if (lane == 0) wsum[wid] = s;
        __syncthreads();
        if (threadIdx.x == 0) {
            const float c0 = ws[NBLOCKS], c1 = ws[NBLOCKS + 1];
            out[0] = -(wsum[0] + wsum[1] + wsum[2] + wsum[3]) / (c0 * c0 + c1 * c1);
        }
    }
}

extern "C" void kernel_launch(void* const* d_in, const int* in_sizes, int n_in,
                              void* d_out, int out_size, void* d_ws, size_t ws_size,
                              hipStream_t stream) {
    const float* pred = (const float*)d_in[0];
    const float* nat  = (const float*)d_in[1];
    const int*   mask = (const int*)d_in[2];
    float* out = (float*)d_out;
    float* ws  = (float*)d_ws;

    // d0 = 1.24 * (512 - 15)^(1/3) - 1.8  (host-side pure math, capture-safe)
    const double d0 = 1.24 * cbrt(512.0 - 15.0) - 1.8;
    const float inv_d0 = (float)(1.0 / d0);

    void* args[] = { (void*)&pred, (void*)&nat, (void*)&mask,
                     (void*)&ws, (void*)&out, (void*)&inv_d0 };
    hipLaunchCooperativeKernel((const void*)fused_kernel,
                               dim3(NBLOCKS), dim3(THREADS),
                               args, 0, stream);
}

// Round 3
// 15.062 us; speedup vs baseline: 8.0463x; 8.0463x over previous
//
#include <hip/hip_runtime.h>
#include <math.h>

// Problem constants (B=2, N_RES=512, N_ATOMS=4)
#define NPTS    2048                    // points per batch
#define BATCH   2
#define TOTAL_I (BATCH * NPTS)          // 4096
#define THREADS 256
#define IBLOCKS (TOTAL_I / THREADS)     // 16 i-groups
#define JCHUNKS 64
#define JLEN    (NPTS / JCHUNKS)        // 32 j-iterations per thread
#define NBLOCKS (IBLOCKS * JCHUNKS)     // 1024 blocks -> 4 per CU

__global__ __launch_bounds__(THREADS) void pair_loss_kernel(
    const float* __restrict__ pred, const float* __restrict__ nat,
    const int* __restrict__ mask, float* __restrict__ ws, float inv_d0)
{
    __shared__ float wsum[THREADS / 64];

    const int bid   = blockIdx.x;
    const int chunk = bid >> 4;                   // 0..63, block-uniform
    const int ig    = bid & (IBLOCKS - 1);        // 0..15
    const int b     = ig >> 3;                    // block-uniform batch
    const int i     = (ig & 7) * THREADS + threadIdx.x;
    const int lane  = threadIdx.x & 63;
    const int wid   = threadIdx.x >> 6;

    const float* __restrict__ pb = pred + (size_t)(b * NPTS * 3);
    const float* __restrict__ nb = nat  + (size_t)(b * NPTS * 3);
    const int*   __restrict__ mb = mask + b * NPTS;

    // per-lane i-point coords in registers
    const float pix = pb[i*3+0], piy = pb[i*3+1], piz = pb[i*3+2];
    const float nix = nb[i*3+0], niy = nb[i*3+1], niz = nb[i*3+2];
    const int   mi  = mb[i];

    float acc = 0.0f;
    const int j0 = chunk * JLEN;
    #pragma unroll 8
    for (int jj = 0; jj < JLEN; ++jj) {
        const int j = j0 + jj;                    // block-uniform address stream
        const float dx = pix - pb[j*3+0];
        const float dy = piy - pb[j*3+1];
        const float dz = piz - pb[j*3+2];
        const float pd = __builtin_amdgcn_sqrtf(dx*dx + dy*dy + dz*dz);
        const float ex = nix - nb[j*3+0];
        const float ey = niy - nb[j*3+1];
        const float ez = niz - nb[j*3+2];
        const float nd = __builtin_amdgcn_sqrtf(ex*ex + ey*ey + ez*ez);
        const float t    = (pd - nd) * inv_d0;
        const float prox = __builtin_amdgcn_rcpf(1.0f + t*t);
        acc += (mb[j] != 0) ? prox : 0.0f;
    }
    if (mi == 0) acc = 0.0f;

    // wave reduce, cross-wave via LDS, overwrite block partial (no init needed)
    for (int off = 32; off > 0; off >>= 1)
        acc += __shfl_down(acc, off, 64);
    if (lane == 0) wsum[wid] = acc;
    __syncthreads();
    if (threadIdx.x == 0)
        ws[bid] = wsum[0] + wsum[1] + wsum[2] + wsum[3];
}

__global__ __launch_bounds__(1024) void finalize_kernel(
    const int* __restrict__ mask, const float* __restrict__ ws,
    float* __restrict__ out)
{
    __shared__ float red[16], c0s[16], c1s[16];
    const int tid = threadIdx.x, lane = tid & 63, wid = tid >> 6;

    float s  = ws[tid];                            // 1024 partials
    int   l0 = (mask[tid]        != 0) + (mask[tid + 1024] != 0);   // batch 0
    int   l1 = (mask[tid + 2048] != 0) + (mask[tid + 3072] != 0);   // batch 1

    for (int off = 32; off > 0; off >>= 1) {
        s  += __shfl_down(s,  off, 64);
        l0 += __shfl_down(l0, off, 64);
        l1 += __shfl_down(l1, off, 64);
    }
    if (lane == 0) { red[wid] = s; c0s[wid] = (float)l0; c1s[wid] = (float)l1; }
    __syncthreads();
    if (tid == 0) {
        float S = 0.f, C0 = 0.f, C1 = 0.f;
        #pragma unroll
        for (int w = 0; w < 16; ++w) { S += red[w]; C0 += c0s[w]; C1 += c1s[w]; }
        out[0] = -S / (C0 * C0 + C1 * C1);
    }
}

extern "C" void kernel_launch(void* const* d_in, const int* in_sizes, int n_in,
                              void* d_out, int out_size, void* d_ws, size_t ws_size,
                              hipStream_t stream) {
    const float* pred = (const float*)d_in[0];
    const float* nat  = (const float*)d_in[1];
    const int*   mask = (const int*)d_in[2];
    float* out = (float*)d_out;
    float* ws  = (float*)d_ws;

    // d0 = 1.24 * (512 - 15)^(1/3) - 1.8  (host-side pure math, capture-safe)
    const double d0 = 1.24 * cbrt(512.0 - 15.0) - 1.8;
    const float inv_d0 = (float)(1.0 / d0);

    pair_loss_kernel<<<NBLOCKS, THREADS, 0, stream>>>(pred, nat, mask, ws, inv_d0);
    finalize_kernel<<<1, 1024, 0, stream>>>(mask, ws, out);
}